// Round 1
// baseline (446.640 us; speedup 1.0000x reference)
//
#include <hip/hip_runtime.h>
#include <hip/hip_bf16.h>

#define D 64

// Kernel 1: per-node precompute.
// sd[n] = { h[n]·w_dst + gate_b, dnorm[n] }   (used when n is a dst)
// ss[n] = { h[n]·w_src,          dnorm[n] }   (used when n is a src)
__global__ void fal_precompute(const float* __restrict__ h,
                               const float* __restrict__ dnorm,
                               const float* __restrict__ gate_w,
                               const float* __restrict__ gate_b,
                               float2* __restrict__ sd,
                               float2* __restrict__ ss,
                               int N) {
    int wave = (int)((blockIdx.x * blockDim.x + threadIdx.x) >> 6);
    int lane = threadIdx.x & 63;
    if (wave >= N) return;

    float hv = h[wave * D + lane];
    float a = hv * gate_w[lane];        // w_dst[lane]
    float b = hv * gate_w[D + lane];    // w_src[lane]

    // full 64-lane butterfly reduction
    for (int off = 32; off > 0; off >>= 1) {
        a += __shfl_xor(a, off, 64);
        b += __shfl_xor(b, off, 64);
    }
    if (lane == 0) {
        float dn = dnorm[wave];
        sd[wave] = make_float2(a + gate_b[0], dn);
        ss[wave] = make_float2(b, dn);
    }
}

// Kernel 2: edge phase. One wave handles a chunk of 64 edges.
// Scalar phase: lane i computes edge (base+i)'s gate scalar.
// Row phase: broadcast (s, d, e) per edge; lane d does h[s][d]*e -> atomicAdd z[d][d].
__global__ void fal_edges(const float* __restrict__ h,
                          const int* __restrict__ src,
                          const int* __restrict__ dst,
                          const float2* __restrict__ sd,
                          const float2* __restrict__ ss,
                          float* __restrict__ z,
                          int E) {
    int wave = (int)((blockIdx.x * blockDim.x + threadIdx.x) >> 6);
    int lane = threadIdx.x & 63;

    long base = (long)wave * 64;
    if (base >= E) return;

    int s = 0, d = 0;
    float escal = 0.0f;
    long e = base + lane;
    if (e < E) {
        s = src[e];
        d = dst[e];
        float2 ad = sd[d];
        float2 bs = ss[s];
        float g = tanhf(ad.x + bs.x);   // bias already folded into sd.x
        escal = g * ad.y * bs.y;
    }

    int cnt = (int)min((long)64, E - base);
    for (int j = 0; j < cnt; ++j) {
        int   sj = __shfl(s,     j, 64);
        int   dj = __shfl(d,     j, 64);
        float ej = __shfl(escal, j, 64);
        float val = h[(long)sj * D + lane] * ej;
        atomicAdd(&z[(long)dj * D + lane], val);
    }
}

extern "C" void kernel_launch(void* const* d_in, const int* in_sizes, int n_in,
                              void* d_out, int out_size, void* d_ws, size_t ws_size,
                              hipStream_t stream) {
    const float* h      = (const float*)d_in[0];
    const float* dnorm  = (const float*)d_in[1];
    const float* gate_w = (const float*)d_in[2];
    const float* gate_b = (const float*)d_in[3];
    const int*   src    = (const int*)d_in[4];
    const int*   dst    = (const int*)d_in[5];
    float*       z      = (float*)d_out;

    int N = in_sizes[1];           // 100000
    int E = in_sizes[4];           // 1600000

    float2* sd = (float2*)d_ws;
    float2* ss = sd + N;

    // z must start at zero (harness poisons d_out with 0xAA)
    hipMemsetAsync(d_out, 0, (size_t)out_size * sizeof(float), stream);

    // Precompute per-node scalars: one wave per node, 4 waves/block.
    {
        int waves = N;
        int blocks = (waves + 3) / 4;
        fal_precompute<<<blocks, 256, 0, stream>>>(h, dnorm, gate_w, gate_b, sd, ss, N);
    }

    // Edge phase: one wave per 64 edges, 4 waves/block.
    {
        long chunks = ((long)E + 63) / 64;
        int blocks = (int)((chunks + 3) / 4);
        fal_edges<<<blocks, 256, 0, stream>>>(h, src, dst, sd, ss, z, E);
    }
}

// Round 2
// 308.655 us; speedup vs baseline: 1.4471x; 1.4471x over previous
//
#include <hip/hip_runtime.h>
#include <hip/hip_bf16.h>

#define D 64

// ---------------- Kernel 1: per-node gate scalars ----------------
// sd[n] = { h[n]·w_dst + gate_b, dnorm[n] },  ss[n] = { h[n]·w_src, dnorm[n] }
// 16 lanes per node, float4 loads; wave handles 4 nodes, block handles 16.
__global__ void fal_precompute(const float* __restrict__ h,
                               const float* __restrict__ dnorm,
                               const float* __restrict__ gate_w,
                               const float* __restrict__ gate_b,
                               float2* __restrict__ sd,
                               float2* __restrict__ ss,
                               int N) {
    int tid  = threadIdx.x;
    int lane = tid & 63;
    int wave = tid >> 6;              // 0..3
    int grp  = lane >> 4;             // 0..3 (node group within wave)
    int gl   = lane & 15;             // lane within group

    int node = blockIdx.x * 16 + wave * 4 + grp;
    int nc   = node < N ? node : N - 1;   // clamp loads, guard stores

    const float4* h4 = (const float4*)h;
    const float4* w4 = (const float4*)gate_w;

    float4 hv = h4[nc * 16 + gl];
    float4 wd = w4[gl];          // w_dst
    float4 wsr = w4[16 + gl];    // w_src

    float a = hv.x * wd.x + hv.y * wd.y + hv.z * wd.z + hv.w * wd.w;
    float b = hv.x * wsr.x + hv.y * wsr.y + hv.z * wsr.z + hv.w * wsr.w;

    // reduce across the 16-lane group (xor masks stay in-group)
    for (int off = 1; off < 16; off <<= 1) {
        a += __shfl_xor(a, off, 64);
        b += __shfl_xor(b, off, 64);
    }

    if (gl == 0 && node < N) {
        float dn = dnorm[node];
        sd[node] = make_float2(a + gate_b[0], dn);
        ss[node] = make_float2(b, dn);
    }
}

// ---------------- Kernel 2: dst histogram ----------------
__global__ void fal_histogram(const int* __restrict__ dst,
                              int* __restrict__ deg, int E) {
    int e = blockIdx.x * blockDim.x + threadIdx.x;
    if (e < E) atomicAdd(&deg[dst[e]], 1);
}

// ---------------- Kernel 3: order-free region assignment ----------------
// Wave-level exclusive scan of deg + one atomicAdd per wave on a global counter.
__global__ void fal_assign(const int* __restrict__ deg,
                           int* __restrict__ start,
                           int* __restrict__ cursor,
                           int* __restrict__ total, int N) {
    int tid  = blockIdx.x * blockDim.x + threadIdx.x;
    int lane = threadIdx.x & 63;

    int d = (tid < N) ? deg[tid] : 0;

    // inclusive scan across 64 lanes
    int v = d;
    for (int off = 1; off < 64; off <<= 1) {
        int t = __shfl_up(v, off, 64);
        if (lane >= off) v += t;
    }
    int wave_total = __shfl(v, 63, 64);

    int base = 0;
    if (lane == 63) base = atomicAdd(total, wave_total);
    base = __shfl(base, 63, 64);

    int st = base + v - d;   // exclusive prefix
    if (tid < N) {
        start[tid]  = st;
        cursor[tid] = st;
    }
}

// ---------------- Kernel 4: scatter edges into per-dst regions ----------------
// Packs (src, gate_scalar) as int2 — one 8B store per edge.
__global__ void fal_scatter(const int* __restrict__ src,
                            const int* __restrict__ dst,
                            const float2* __restrict__ sd,
                            const float2* __restrict__ ss,
                            int* __restrict__ cursor,
                            int2* __restrict__ perm, int E) {
    int e = blockIdx.x * blockDim.x + threadIdx.x;
    if (e >= E) return;
    int s  = src[e];
    int dd = dst[e];
    float2 ad = sd[dd];
    float2 bs = ss[s];
    float g   = tanhf(ad.x + bs.x);       // bias folded into sd.x
    float esc = g * ad.y * bs.y;
    int pos = atomicAdd(&cursor[dd], 1);
    perm[pos] = make_int2(s, __float_as_int(esc));
}

// ---------------- Kernel 5: per-node accumulation (no atomics) ----------------
// One wave per dst node; lane = dim. Unroll-4 prefetch of gathered h rows.
__global__ void fal_accumulate(const float* __restrict__ h,
                               const int* __restrict__ start,
                               const int* __restrict__ deg,
                               const int2* __restrict__ perm,
                               float* __restrict__ z, int N) {
    int wave = (int)((blockIdx.x * blockDim.x + threadIdx.x) >> 6);
    int lane = threadIdx.x & 63;
    if (wave >= N) return;

    int rs = start[wave];
    int re = rs + deg[wave];

    float acc = 0.0f;
    for (int k0 = rs; k0 < re; k0 += 64) {
        int cnt = min(64, re - k0);
        int2 pe = make_int2(0, 0);
        if (k0 + lane < re) pe = perm[k0 + lane];
        int   ms = pe.x;
        float me = __int_as_float(pe.y);

        int j = 0;
        for (; j + 4 <= cnt; j += 4) {
            int   s0 = __shfl(ms, j,     64), s1 = __shfl(ms, j + 1, 64);
            int   s2 = __shfl(ms, j + 2, 64), s3 = __shfl(ms, j + 3, 64);
            float e0 = __shfl(me, j,     64), e1 = __shfl(me, j + 1, 64);
            float e2 = __shfl(me, j + 2, 64), e3 = __shfl(me, j + 3, 64);
            float v0 = h[s0 * D + lane];
            float v1 = h[s1 * D + lane];
            float v2 = h[s2 * D + lane];
            float v3 = h[s3 * D + lane];
            acc = fmaf(v0, e0, acc);
            acc = fmaf(v1, e1, acc);
            acc = fmaf(v2, e2, acc);
            acc = fmaf(v3, e3, acc);
        }
        for (; j < cnt; ++j) {
            int   sj = __shfl(ms, j, 64);
            float ej = __shfl(me, j, 64);
            acc = fmaf(h[sj * D + lane], ej, acc);
        }
    }
    z[wave * D + lane] = acc;   // covers every node, incl. deg==0 -> 0
}

extern "C" void kernel_launch(void* const* d_in, const int* in_sizes, int n_in,
                              void* d_out, int out_size, void* d_ws, size_t ws_size,
                              hipStream_t stream) {
    const float* h      = (const float*)d_in[0];
    const float* dnorm  = (const float*)d_in[1];
    const float* gate_w = (const float*)d_in[2];
    const float* gate_b = (const float*)d_in[3];
    const int*   src    = (const int*)d_in[4];
    const int*   dst    = (const int*)d_in[5];
    float*       z      = (float*)d_out;

    int N = in_sizes[1];   // 100000
    int E = in_sizes[4];   // 1600000

    // ---- workspace layout ----
    char* ws = (char*)d_ws;
    float2* sd     = (float2*)ws;                  ws += (size_t)N * sizeof(float2);
    float2* ss     = (float2*)ws;                  ws += (size_t)N * sizeof(float2);
    int*    deg    = (int*)ws;                     ws += (size_t)N * sizeof(int);
    int*    total  = (int*)ws;                     ws += 16;                // padded
    int*    start  = (int*)ws;                     ws += (size_t)N * sizeof(int);
    int*    cursor = (int*)ws;                     ws += (size_t)N * sizeof(int);
    int2*   perm   = (int2*)ws;                    // E * 8 bytes

    // zero deg + total in one async memset (they are adjacent)
    hipMemsetAsync(deg, 0, (size_t)N * sizeof(int) + 16, stream);

    // 1. per-node scalars: 16 nodes/block
    fal_precompute<<<(N + 15) / 16, 256, 0, stream>>>(h, dnorm, gate_w, gate_b, sd, ss, N);

    // 2. histogram
    fal_histogram<<<(E + 255) / 256, 256, 0, stream>>>(dst, deg, E);

    // 3. region assignment (order-free)
    fal_assign<<<(N + 255) / 256, 256, 0, stream>>>(deg, start, cursor, total, N);

    // 4. scatter (src, gate scalar) into per-dst regions
    fal_scatter<<<(E + 255) / 256, 256, 0, stream>>>(src, dst, sd, ss, cursor, perm, E);

    // 5. accumulate: 1 wave/node, 4 waves/block
    fal_accumulate<<<(N + 3) / 4, 256, 0, stream>>>(h, start, deg, perm, z, N);
}